// Round 1
// baseline (5901.535 us; speedup 1.0000x reference)
//
#include <hip/hip_runtime.h>
#include <hip/hip_bf16.h>

// PathRNN: h_{t+1} = tanh(x_t + W_hh h_t), u = h, pos = u @ W_out^T
// B=128, T=1024, H=512.
// Decomposition: 8 batch-groups (16 batches) x 8 N-slice WGs (64 cols) = 64 WGs.
// Per step each WG: MFMA 16x16x32 bf16 (W in regs, h in swizzled LDS),
// publish own 16x64 bf16 slice via agent-scope atomics (L3-coherent),
// spin on group flags, gather 7 remote slices into LDS for next step.

#define TT 1024
#define BB 128
#define HH 512

typedef short s16x8 __attribute__((ext_vector_type(8)));
typedef float f32x4 __attribute__((ext_vector_type(4)));
typedef unsigned int uint;
typedef unsigned short ushort_t;

#define MFMA_B16(a, b, c) __builtin_amdgcn_mfma_f32_16x16x32_bf16((a), (b), (c), 0, 0, 0)

__device__ __forceinline__ ushort_t bf16_rne(float f) {
  uint u = __float_as_uint(f);
  u += 0x7fffu + ((u >> 16) & 1u);  // round-to-nearest-even
  return (ushort_t)(u >> 16);
}

__device__ __forceinline__ float tanh_fast(float z) {
  // tanh(z) = 1 - 2/(exp(2z)+1); exact at +-inf saturation, ~1e-6 rel err.
  float e = __expf(2.0f * z);
  return 1.0f - 2.0f * __builtin_amdgcn_rcpf(e + 1.0f);
}

__global__ __launch_bounds__(256) void rnn_kernel(
    const float* __restrict__ vel, const float* __restrict__ W_ih,
    const float* __restrict__ W_hh, const float* __restrict__ b_ih,
    const float* __restrict__ b_hh, float* __restrict__ u_out,
    uint* __restrict__ flags, uint* __restrict__ pub) {
  // LDS: [slot 2][b 16][k 512] bf16, byte addr ^ ((b&7)<<4) swizzle
  __shared__ uint4 hlds_mem[2048];  // 32 KiB
  char* hlds = (char*)hlds_mem;

  const int tid = threadIdx.x;
  const int lane = tid & 63;
  const int w = tid >> 6;   // wave 0..3
  const int bid = blockIdx.x;
  const int g = bid & 7;    // batch group (bid&7 -> same XCD per group, heuristic only)
  const int i = bid >> 3;   // N-slice index 0..7
  const int b0 = g * 16;
  const int l15 = lane & 15;  // A: batch row / B: out col / C: out col
  const int kg = lane >> 4;   // k-group 0..3
  const int nw = i * 64 + w * 16;
  const int n_x = nw + l15;   // this lane's output column (0..511)

  // ---- one-time: preload W_hh B-frags into registers (bf16 RNE) ----
  s16x8 wreg[16];
#pragma unroll
  for (int kt = 0; kt < 16; ++kt) {
    const float* wp = W_hh + (size_t)n_x * HH + kt * 32 + kg * 8;
    float4 lo = *(const float4*)wp;
    float4 hi = *(const float4*)(wp + 4);
    s16x8 s;
    s[0] = (short)bf16_rne(lo.x); s[1] = (short)bf16_rne(lo.y);
    s[2] = (short)bf16_rne(lo.z); s[3] = (short)bf16_rne(lo.w);
    s[4] = (short)bf16_rne(hi.x); s[5] = (short)bf16_rne(hi.y);
    s[6] = (short)bf16_rne(hi.z); s[7] = (short)bf16_rne(hi.w);
    wreg[kt] = s;
  }
  const float wih0 = W_ih[n_x * 2 + 0];
  const float wih1 = W_ih[n_x * 2 + 1];
  const float bsum = b_ih[n_x] + b_hh[n_x];

  // ---- zero h slot 0 (h_0 = 0) ----
  {
    uint4 z = {0u, 0u, 0u, 0u};
    uint4* p = (uint4*)(hlds + tid * 64);
    p[0] = z; p[1] = z; p[2] = z; p[3] = z;
  }
  __syncthreads();

  for (int t = 0; t < TT; ++t) {
    const int cur = t & 1;
    const int nxt = cur ^ 1;

    // prefetch vel for this step (hidden under MFMA phase)
    float2 v[4];
#pragma unroll
    for (int r = 0; r < 4; ++r) {
      int bl = kg * 4 + r;
      v[r] = *(const float2*)(vel + ((size_t)(b0 + bl) * TT + t) * 2);
    }

    // ---- MFMA: acc[16 b x 16 n] over K=512 (16 k-tiles, 2 chained accumulators)
    f32x4 acc0 = {0.f, 0.f, 0.f, 0.f};
    f32x4 acc1 = {0.f, 0.f, 0.f, 0.f};
#pragma unroll
    for (int kt = 0; kt < 16; ++kt) {
      uint logical = (uint)cur * 16384u + (uint)l15 * 1024u + (uint)kt * 64u + (uint)kg * 16u;
      uint phys = logical ^ (((uint)l15 & 7u) << 4);
      s16x8 a = *(const s16x8*)(hlds + phys);
      if (kt & 1) acc1 = MFMA_B16(a, wreg[kt], acc1);
      else        acc0 = MFMA_B16(a, wreg[kt], acc0);
    }
    f32x4 acc = acc0 + acc1;

    // ---- epilogue: x + tanh, store u (fp32), write own h_new slice to LDS[nxt]
#pragma unroll
    for (int r = 0; r < 4; ++r) {
      int bl = kg * 4 + r;  // C row = (lane>>4)*4 + reg
      float x = fmaf(v[r].x, wih0, fmaf(v[r].y, wih1, bsum));
      float uval = tanh_fast(x + acc[r]);
      __builtin_nontemporal_store(uval, u_out + ((size_t)(b0 + bl) * TT + t) * HH + n_x);
      ushort_t hb = bf16_rne(uval);
      uint logical = (uint)nxt * 16384u + (uint)bl * 1024u + (uint)n_x * 2u;
      *(ushort_t*)(hlds + (logical ^ (((uint)bl & 7u) << 4))) = hb;
    }

    if (t == TT - 1) break;  // h_{T} not needed by anyone

    __syncthreads();  // own slice complete in LDS[nxt]

    // ---- publish own slice (wave 0): LDS -> pub[nxt][g][i], then flag = t+1
    if (w == 0) {
      uint row = (uint)lane >> 2;   // 0..15
      uint blk = (uint)lane & 3u;   // 0..3 (32B chunks)
      uint logical = (uint)nxt * 16384u + row * 1024u + (uint)i * 128u + blk * 32u;
      uint phys = logical ^ ((row & 7u) << 4);
      uint4 d0 = *(const uint4*)(hlds + phys);
      uint4 d1 = *(const uint4*)(hlds + (phys ^ 16u));
      uint* dst = pub + (((uint)nxt * 8u + (uint)g) * 8u + (uint)i) * 512u + row * 32u + blk * 8u;
      __hip_atomic_store(dst + 0, d0.x, __ATOMIC_RELAXED, __HIP_MEMORY_SCOPE_AGENT);
      __hip_atomic_store(dst + 1, d0.y, __ATOMIC_RELAXED, __HIP_MEMORY_SCOPE_AGENT);
      __hip_atomic_store(dst + 2, d0.z, __ATOMIC_RELAXED, __HIP_MEMORY_SCOPE_AGENT);
      __hip_atomic_store(dst + 3, d0.w, __ATOMIC_RELAXED, __HIP_MEMORY_SCOPE_AGENT);
      __hip_atomic_store(dst + 4, d1.x, __ATOMIC_RELAXED, __HIP_MEMORY_SCOPE_AGENT);
      __hip_atomic_store(dst + 5, d1.y, __ATOMIC_RELAXED, __HIP_MEMORY_SCOPE_AGENT);
      __hip_atomic_store(dst + 6, d1.z, __ATOMIC_RELAXED, __HIP_MEMORY_SCOPE_AGENT);
      __hip_atomic_store(dst + 7, d1.w, __ATOMIC_RELAXED, __HIP_MEMORY_SCOPE_AGENT);
      __builtin_amdgcn_fence(__ATOMIC_RELEASE, "agent");
      if (lane == 0) {
        __hip_atomic_store(&flags[g * 8 + i], (uint)(t + 1), __ATOMIC_RELAXED,
                           __HIP_MEMORY_SCOPE_AGENT);
      }
    }

    // ---- spin on 7 peer flags (wave 1, lanes 0..6) ----
    if (w == 1 && lane < 7) {
      int jj = lane + (lane >= i ? 1 : 0);
      while (__hip_atomic_load(&flags[g * 8 + jj], __ATOMIC_RELAXED,
                               __HIP_MEMORY_SCOPE_AGENT) < (uint)(t + 1)) {
      }
    }
    __syncthreads();  // all peers published
    __builtin_amdgcn_fence(__ATOMIC_ACQUIRE, "agent");

    // ---- gather 7 remote slices -> LDS[nxt] (512 dwords each / 256 lanes) ----
#pragma unroll
    for (int s = 0; s < 7; ++s) {
      int j = s + (s >= i ? 1 : 0);
      const uint* src = pub + (((uint)nxt * 8u + (uint)g) * 8u + (uint)j) * 512u;
#pragma unroll
      for (int q = 0; q < 2; ++q) {
        uint d = (uint)tid + (uint)q * 256u;
        uint val = __hip_atomic_load(src + d, __ATOMIC_RELAXED, __HIP_MEMORY_SCOPE_AGENT);
        uint row = d >> 5;
        uint logical = (uint)nxt * 16384u + row * 1024u + (uint)j * 128u + (d & 31u) * 4u;
        *(uint*)(hlds + (logical ^ ((row & 7u) << 4))) = val;
      }
    }
    __syncthreads();  // h_{t+1} fully assembled
  }
}

__global__ void init_kernel(uint* flags) {
  __hip_atomic_store(&flags[threadIdx.x], 0u, __ATOMIC_RELAXED, __HIP_MEMORY_SCOPE_AGENT);
}

// pos[b,t,:] = u[b,t,:] @ W_out^T + b_out ; one wave per (b,t) row, BW-bound.
__global__ __launch_bounds__(256) void pos_kernel(const float* __restrict__ u,
                                                  const float* __restrict__ W_out,
                                                  const float* __restrict__ b_out,
                                                  float* __restrict__ pos) {
  int row = blockIdx.x * 4 + (threadIdx.x >> 6);
  int lane = threadIdx.x & 63;
  const float* ur = u + (size_t)row * HH + lane * 8;
  float4 u0 = *(const float4*)ur;
  float4 u1 = *(const float4*)(ur + 4);
  float4 w00 = *(const float4*)(W_out + lane * 8);
  float4 w01 = *(const float4*)(W_out + lane * 8 + 4);
  float4 w10 = *(const float4*)(W_out + HH + lane * 8);
  float4 w11 = *(const float4*)(W_out + HH + lane * 8 + 4);
  float p0 = u0.x * w00.x + u0.y * w00.y + u0.z * w00.z + u0.w * w00.w +
             u1.x * w01.x + u1.y * w01.y + u1.z * w01.z + u1.w * w01.w;
  float p1 = u0.x * w10.x + u0.y * w10.y + u0.z * w10.z + u0.w * w10.w +
             u1.x * w11.x + u1.y * w11.y + u1.z * w11.z + u1.w * w11.w;
#pragma unroll
  for (int off = 32; off; off >>= 1) {
    p0 += __shfl_xor(p0, off);
    p1 += __shfl_xor(p1, off);
  }
  if (lane == 0) {
    pos[(size_t)row * 2 + 0] = p0 + b_out[0];
    pos[(size_t)row * 2 + 1] = p1 + b_out[1];
  }
}

extern "C" void kernel_launch(void* const* d_in, const int* in_sizes, int n_in,
                              void* d_out, int out_size, void* d_ws, size_t ws_size,
                              hipStream_t stream) {
  const float* vel   = (const float*)d_in[0];
  const float* W_ih  = (const float*)d_in[1];
  const float* W_hh  = (const float*)d_in[2];
  const float* b_ih  = (const float*)d_in[3];
  const float* b_hh  = (const float*)d_in[4];
  const float* W_out = (const float*)d_in[5];
  const float* b_out = (const float*)d_in[6];

  float* pos = (float*)d_out;                       // [B,T,2]
  float* u   = pos + (size_t)BB * TT * 2;           // [B,T,H]

  // workspace: flags (64 x u32, at offset 0) + pub (2 slots x 8 g x 8 i x 512 dwords)
  uint* flags = (uint*)d_ws;
  uint* pub = flags + 1024;  // 4 KiB offset; total need ~260 KiB of d_ws

  init_kernel<<<1, 64, 0, stream>>>(flags);
  rnn_kernel<<<64, 256, 0, stream>>>(vel, W_ih, W_hh, b_ih, b_hh, u, flags, pub);
  pos_kernel<<<(BB * TT) / 4, 256, 0, stream>>>(u, W_out, b_out, pos);
}